// Round 6
// baseline (3050.948 us; speedup 1.0000x reference)
//
#include <hip/hip_runtime.h>

#define Bz 32
#define Tz 64
#define Sz 128
#define Dz 256
#define Vz 32000

__device__ __forceinline__ float sigmf(float x){ return 1.0f/(1.0f + __expf(-x)); }
__device__ __forceinline__ float tanhfast(float x){ float e = __expf(2.0f*x); return 1.0f - 2.0f/(e+1.0f); }

// ---------------- K1: keys = enc_out @ Wk + bk  ([32,128,256]) + flag reset ----------------
__global__ void k_keys(const float* __restrict__ enc, const float* __restrict__ Wk,
                       const float* __restrict__ bk, float* __restrict__ keys,
                       unsigned* __restrict__ flags){
  const int blk = blockIdx.x;   // 256 blocks = 32 b x 8 s-chunks
  const int tid = threadIdx.x;  // 256
  if (blk == 0) flags[tid] = 0u;   // reset all 256 flags (kernel boundary publishes)
  const int b  = blk >> 3;
  const int s0 = (blk & 7) * 16;
  const float* ebase = enc + (b*Sz + s0)*Dz;
  const int d = tid;
  float acc[16];
  #pragma unroll
  for (int i = 0; i < 16; ++i) acc[i] = 0.f;
  for (int k = 0; k < Dz; k += 4){
    float w0 = Wk[(k+0)*Dz + d];
    float w1 = Wk[(k+1)*Dz + d];
    float w2 = Wk[(k+2)*Dz + d];
    float w3 = Wk[(k+3)*Dz + d];
    #pragma unroll
    for (int si = 0; si < 16; ++si){
      float4 ev = *(const float4*)(ebase + si*Dz + k);
      acc[si] += ev.x*w0 + ev.y*w1 + ev.z*w2 + ev.w*w3;
    }
  }
  const float bkd = bk[d];
  #pragma unroll
  for (int si = 0; si < 16; ++si)
    keys[(b*Sz + s0 + si)*Dz + d] = acc[si] + bkd;
}

// ---------------- MEGA-KERNEL: blocks 0..255 recurrence, blocks 256..505 logits workers -----
// Recur block (b,s): owns 32 h-units; gate weights (emb||h) in 64 regs; Wq slice in 32 regs;
// encW slice computed directly into LDS (64 KB). One flag-synced L3 exchange per step
// (relaxed agent atomics only — NO agent fences, L2 stays warm). hs published via atomic
// stores; workers trail the recurrence, computing exp(hs@Wo+bo) 128x128 tiles per R-chunk
// as soon as flags show all rows finished that chunk's 4 timesteps. Workers never block
// recur; all 506 blocks co-resident (1024 thr, <=8 waves/EU, LDS 74.5KB<=80KB) => no deadlock.
__global__ void __launch_bounds__(1024, 8) k_mega(
    const int* __restrict__ tok, const float* __restrict__ h0, const float* __restrict__ c0,
    const float* __restrict__ enc, const float* __restrict__ Emb,
    const float* __restrict__ Wq, const float* __restrict__ bq,
    const float* __restrict__ Vw, const float* __restrict__ bv,
    const float* __restrict__ Wx, const float* __restrict__ Wh,
    const float* __restrict__ bl, const float* __restrict__ Wo,
    const float* __restrict__ bo, const float* __restrict__ keys,
    float* __restrict__ hs, float* xch, unsigned* flags,
    float* __restrict__ out, float* __restrict__ part)
{
  __shared__ float smem[18628];   // 74512 B (recur layout; worker uses a prefix)
  const int tid = threadIdx.x;

  if (blockIdx.x < 256){
    // ================= RECURRENCE ROLE =================
    const int blk = blockIdx.x;
    const int b = ((blk >> 6) << 3) | (blk & 7);   // row (blk%8 == b%8: same-XCD heuristic)
    const int s = (blk >> 3) & 7;                  // unit-slice

    float* ew    = smem;           // [128 s][128 u_local]
    float* xe    = ew + 16384;     // [emb(256) || h(256)]
    float* qv    = xe + 512;       // 256
    float* vl    = qv + 256;       // 256
    float* selds = vl + 256;       // 129 (pad 132)
    float* zp    = selds + 132;    // [kc(8)][u_local(128)]
    float* hnl   = zp + 1024;      // 32
    float* clds  = hnl + 32;       // 32

    const int u_local = tid & 127;
    const int kc = tid >> 7;                                   // 0..7
    const int u_gate = ((u_local >> 5) << 8) + (s << 5) + (u_local & 31);

    // --- prologue: encW slice -> LDS (thread (ul, sc=kc) accumulates 16 s-rows) ---
    {
      float acc[16];
      #pragma unroll
      for (int i = 0; i < 16; ++i) acc[i] = 0.f;
      const float* eb = enc + (size_t)(b*Sz + kc*16)*Dz;
      for (int d4 = 0; d4 < Dz; d4 += 4){
        float w0 = Wx[(size_t)(d4+0)*1024 + u_gate];
        float w1 = Wx[(size_t)(d4+1)*1024 + u_gate];
        float w2 = Wx[(size_t)(d4+2)*1024 + u_gate];
        float w3 = Wx[(size_t)(d4+3)*1024 + u_gate];
        #pragma unroll
        for (int i = 0; i < 16; ++i){
          float4 ev = *(const float4*)(eb + (size_t)i*Dz + d4);
          acc[i] += ev.x*w0 + ev.y*w1 + ev.z*w2 + ev.w*w3;
        }
      }
      #pragma unroll
      for (int i = 0; i < 16; ++i) ew[(kc*16 + i)*128 + u_local] = acc[i];
    }

    // --- persistent register weights ---
    float w[64];   // gate weights over x = [emb(0..255) || h(256..511)], k = kc*64+i
    {
      const float* wbase = (kc < 4) ? (Wx + (size_t)(256 + kc*64)*1024 + u_gate)
                                    : (Wh + (size_t)((kc-4)*64)*1024 + u_gate);
      #pragma unroll
      for (int i = 0; i < 64; ++i) w[i] = wbase[(size_t)i*1024];
    }
    const int dq = tid & 255;
    float wq[32];  // Wq rows [s*32 .. s*32+32), col dq
    #pragma unroll
    for (int u = 0; u < 32; ++u) wq[u] = Wq[(size_t)(s*32 + u)*Dz + dq];

    if (tid < Dz) vl[tid] = Vw[tid];
    if (tid < 32){ hnl[tid] = h0[b*Dz + s*32 + tid]; clds[tid] = c0[b*Dz + s*32 + tid]; }
    __syncthreads();

    // --- initial publish (parity 0, token 1) + emb prefetch for t=0 ---
    {
      float* xn = xch + (size_t)(b*8 + s)*288;
      if (tid < 256){
        float qp = 0.f;
        #pragma unroll
        for (int u = 0; u < 32; ++u) qp = __builtin_fmaf(hnl[u], wq[u], qp);
        __hip_atomic_store(xn + tid, qp, __ATOMIC_RELAXED, __HIP_MEMORY_SCOPE_AGENT);
      } else if (tid < 288){
        __hip_atomic_store(xn + tid, hnl[tid - 256], __ATOMIC_RELAXED, __HIP_MEMORY_SCOPE_AGENT);
      } else if (tid >= 512 && tid < 768){
        const int tk = tok[b*Tz + 0];
        xe[tid - 512] = Emb[(size_t)tk*Dz + (tid - 512)];
      }
      __syncthreads();   // atomic stores ack'd at L3 (vmcnt drained per-wave)
      if (tid == 0)
        __hip_atomic_store(flags + b*8 + s, 1u, __ATOMIC_RELAXED, __HIP_MEMORY_SCOPE_AGENT);
    }

    const float bv0 = bv[0];
    const int ss = tid >> 3, p8 = tid & 7;

    for (int t = 0; t < Tz; ++t){
      // ---- P0: poll peers (token t+1) ----
      if (tid < 8){
        const unsigned tgt = (unsigned)(t + 1);
        while (__hip_atomic_load(flags + b*8 + tid, __ATOMIC_RELAXED, __HIP_MEMORY_SCOPE_AGENT) < tgt)
          __builtin_amdgcn_s_sleep(1);
      }
      __syncthreads();
      __builtin_amdgcn_fence(__ATOMIC_ACQUIRE, "workgroup");   // ordering only, no cache inv

      const float* xcp = xch + (size_t)((t & 1)*256 + b*8)*288;
      // ---- P1: assemble q and h (emb already prefetched) ----
      if (tid < 256){
        float q = bq[tid];
        #pragma unroll
        for (int s2 = 0; s2 < 8; ++s2)
          q += __hip_atomic_load(xcp + s2*288 + tid, __ATOMIC_RELAXED, __HIP_MEMORY_SCOPE_AGENT);
        qv[tid] = q;
      } else if (tid < 512){
        const int u = tid - 256;
        xe[256 + u] = __hip_atomic_load(xcp + (u >> 5)*288 + 256 + (u & 31),
                                        __ATOMIC_RELAXED, __HIP_MEMORY_SCOPE_AGENT);
      }
      __syncthreads();
      // ---- P2: scores (redundant across slices) + inline exp ----
      {
        const float* kp = keys + (size_t)(b*Sz + ss)*Dz;
        float a = 0.f;
        #pragma unroll
        for (int j4 = 0; j4 < 8; ++j4){
          const int d0 = j4*32 + p8*4;
          float4 kv = *(const float4*)(kp + d0);
          float4 qj = *(const float4*)(qv + d0);
          float4 vj = *(const float4*)(vl + d0);
          a += tanhfast(qj.x + kv.x) * vj.x;
          a += tanhfast(qj.y + kv.y) * vj.y;
          a += tanhfast(qj.z + kv.z) * vj.z;
          a += tanhfast(qj.w + kv.w) * vj.w;
        }
        a += __shfl_down(a, 4);
        a += __shfl_down(a, 2);
        a += __shfl_down(a, 1);
        if (p8 == 0) selds[ss] = __expf(a + bv0);   // scores bounded -> safe without max-sub
      }
      __syncthreads();
      // ---- P3: softmax denom ----
      if (tid < 64){
        float v = selds[tid] + selds[tid + 64];
        #pragma unroll
        for (int off = 32; off > 0; off >>= 1) v += __shfl_down(v, off);
        if (tid == 0) selds[Sz] = 1.0f / v;
      }
      __syncthreads();
      // ---- P4: z partials (register weights + LDS encW) ----
      {
        float acc1 = 0.f;
        const float* xep = xe + kc*64;
        #pragma unroll
        for (int i4 = 0; i4 < 16; ++i4){
          float4 xv = *(const float4*)(xep + i4*4);
          acc1 += xv.x*w[i4*4+0] + xv.y*w[i4*4+1] + xv.z*w[i4*4+2] + xv.w*w[i4*4+3];
        }
        float acc2 = 0.f;
        const float* ewp = ew + kc*16*128 + u_local;
        #pragma unroll
        for (int m = 0; m < 16; ++m)
          acc2 = __builtin_fmaf(selds[kc*16 + m], ewp[m*128], acc2);
        zp[kc*128 + u_local] = acc1 + selds[Sz]*acc2;
      }
      __syncthreads();
      // ---- P5: gate reduce + LSTM + hs publish (atomic: workers read mid-kernel) ----
      if (tid < 32){
        const int u = tid;
        float zi = bl[         s*32 + u], zf = bl[  Dz + s*32 + u];
        float zg = bl[2*Dz + s*32 + u], zo = bl[3*Dz + s*32 + u];
        #pragma unroll
        for (int k2 = 0; k2 < 8; ++k2){
          zi += zp[k2*128 +      u];
          zf += zp[k2*128 + 32 + u];
          zg += zp[k2*128 + 64 + u];
          zo += zp[k2*128 + 96 + u];
        }
        float cn = sigmf(zf)*clds[u] + sigmf(zi)*tanhfast(zg);
        float hn = sigmf(zo)*tanhfast(cn);
        clds[u] = cn; hnl[u] = hn;
        __hip_atomic_store(hs + (size_t)(t*Bz + b)*Dz + s*32 + u, hn,
                           __ATOMIC_RELAXED, __HIP_MEMORY_SCOPE_AGENT);
      }
      __syncthreads();
      // ---- P6: publish next-step exchange + emb prefetch for t+1 ----
      {
        float* xn = xch + (size_t)(((t+1) & 1)*256 + b*8 + s)*288;
        if (tid < 256){
          float qp = 0.f;
          #pragma unroll
          for (int u = 0; u < 32; ++u) qp = __builtin_fmaf(hnl[u], wq[u], qp);
          __hip_atomic_store(xn + tid, qp, __ATOMIC_RELAXED, __HIP_MEMORY_SCOPE_AGENT);
        } else if (tid < 288){
          __hip_atomic_store(xn + tid, hnl[tid - 256], __ATOMIC_RELAXED, __HIP_MEMORY_SCOPE_AGENT);
        } else if (tid >= 512 && tid < 768 && t+1 < Tz){
          const int tk = tok[b*Tz + t + 1];
          xe[tid - 512] = Emb[(size_t)tk*Dz + (tid - 512)];
        }
        __syncthreads();   // drain stores (incl. hs) before flag
        if (tid == 0)
          __hip_atomic_store(flags + b*8 + s, (unsigned)(t + 2), __ATOMIC_RELAXED, __HIP_MEMORY_SCOPE_AGENT);
      }
    }
  } else {
    // ================= LOGITS WORKER ROLE =================
    const int wid = blockIdx.x - 256;   // 0..249  (c-chunk)
    float* As = smem;                   // [32][132]  (k-major, transposed A)
    float* Bs = As + 32*132;            // [32][132]
    float* rs = Bs + 32*132;            // [128][33]

    const int ty = tid >> 5;            // 0..31 -> rows ty*4..+4
    const int tx = tid & 31;            // 0..31 -> cols tx*4..+4
    const int c0 = wid * 128;

    for (int y = 0; y < 16; ++y){
      // wait until all rows finished t = 4y+3  (flag >= 4y+5)
      const unsigned tgt = (unsigned)(4*y + 5);
      for (;;){
        int ok = 1;
        if (tid < 256)
          ok = (__hip_atomic_load(flags + tid, __ATOMIC_RELAXED, __HIP_MEMORY_SCOPE_AGENT) >= tgt);
        if (__syncthreads_count(ok) == 1024) break;
        __builtin_amdgcn_s_sleep(16);
      }
      __builtin_amdgcn_fence(__ATOMIC_ACQUIRE, "workgroup");

      const int R0 = y * 128;
      float acc[4][4];
      #pragma unroll
      for (int i = 0; i < 4; ++i)
        #pragma unroll
        for (int j = 0; j < 4; ++j) acc[i][j] = 0.f;

      for (int k0 = 0; k0 < Dz; k0 += 32){
        { // stage A (atomic L3 loads -- hs only coherent via L3), transpose to [k][r]
          const int r = tid >> 3, kq = tid & 7;
          const float* hp = hs + (size_t)(R0 + r)*Dz + k0 + kq*4;
          float a0 = __hip_atomic_load(hp+0, __ATOMIC_RELAXED, __HIP_MEMORY_SCOPE_AGENT);
          float a1 = __hip_atomic_load(hp+1, __ATOMIC_RELAXED, __HIP_MEMORY_SCOPE_AGENT);
          float a2 = __hip_atomic_load(hp+2, __ATOMIC_RELAXED, __HIP_MEMORY_SCOPE_AGENT);
          float a3 = __hip_atomic_load(hp+3, __ATOMIC_RELAXED, __HIP_MEMORY_SCOPE_AGENT);
          As[(kq*4+0)*132 + r] = a0;
          As[(kq*4+1)*132 + r] = a1;
          As[(kq*4+2)*132 + r] = a2;
          As[(kq*4+3)*132 + r] = a3;
        }
        { // stage B
          const int kk = tid >> 5, c4 = tid & 31;
          float4 wv = *(const float4*)(Wo + (size_t)(k0 + kk)*Vz + c0 + c4*4);
          *(float4*)(Bs + kk*132 + c4*4) = wv;
        }
        __syncthreads();
        #pragma unroll
        for (int kk = 0; kk < 32; ++kk){
          float4 av  = *(const float4*)(As + kk*132 + ty*4);
          float4 bv4 = *(const float4*)(Bs + kk*132 + tx*4);
          float ar[4] = {av.x, av.y, av.z, av.w};
          float br[4] = {bv4.x, bv4.y, bv4.z, bv4.w};
          #pragma unroll
          for (int i = 0; i < 4; ++i)
            #pragma unroll
            for (int j = 0; j < 4; ++j)
              acc[i][j] = __builtin_fmaf(ar[i], br[j], acc[i][j]);
        }
        __syncthreads();
      }
      // epilogue: exp + store + row-sum partials
      float4 bo4 = *(const float4*)(bo + c0 + tx*4);
      #pragma unroll
      for (int i = 0; i < 4; ++i){
        const int R = R0 + ty*4 + i;
        const int orow = (R & 31)*64 + (R >> 5);   // R = t*32+b -> out row b*64+t
        float4 pv;
        pv.x = __expf(acc[i][0] + bo4.x);
        pv.y = __expf(acc[i][1] + bo4.y);
        pv.z = __expf(acc[i][2] + bo4.z);
        pv.w = __expf(acc[i][3] + bo4.w);
        *(float4*)(out + (size_t)orow*Vz + c0 + tx*4) = pv;
        rs[(ty*4+i)*33 + tx] = pv.x + pv.y + pv.z + pv.w;
      }
      __syncthreads();
      if (tid < 128){
        float ssum = 0.f;
        #pragma unroll
        for (int x = 0; x < 32; ++x) ssum += rs[tid*33 + x];
        part[(size_t)wid*2048 + R0 + tid] = ssum;
      }
      __syncthreads();
    }
  }
}

// ---------------- K4: row-sum over 250 col-chunks + out *= 1/sum ----------------
__global__ void __launch_bounds__(256) k_scale(float* __restrict__ out, const float* __restrict__ part){
  const int row = blockIdx.x;              // out-row = b*64 + t
  const int b = row >> 6, tt = row & 63;
  const int R = tt*Bz + b;
  const int tid = threadIdx.x;
  __shared__ float ssum[4];
  float v = (tid < 250) ? part[(size_t)tid*2048 + R] : 0.f;
  #pragma unroll
  for (int off = 32; off > 0; off >>= 1) v += __shfl_down(v, off);
  if ((tid & 63) == 0) ssum[tid >> 6] = v;
  __syncthreads();
  const float inv = 1.0f / (ssum[0] + ssum[1] + ssum[2] + ssum[3]);
  float4* rp = (float4*)(out + (size_t)row*Vz);
  for (int j4 = tid; j4 < Vz/4; j4 += 256){
    float4 x = rp[j4];
    x.x *= inv; x.y *= inv; x.z *= inv; x.w *= inv;
    rp[j4] = x;
  }
}

extern "C" void kernel_launch(void* const* d_in, const int* in_sizes, int n_in,
                              void* d_out, int out_size, void* d_ws, size_t ws_size,
                              hipStream_t stream){
  const int*   tok = (const int*)  d_in[0];
  const float* h0  = (const float*)d_in[1];
  const float* c0  = (const float*)d_in[2];
  const float* enc = (const float*)d_in[3];
  const float* E   = (const float*)d_in[4];
  const float* Wq  = (const float*)d_in[5];
  const float* bq  = (const float*)d_in[6];
  const float* Wk  = (const float*)d_in[7];
  const float* bk  = (const float*)d_in[8];
  const float* Vw  = (const float*)d_in[9];
  const float* bv  = (const float*)d_in[10];
  const float* Wx  = (const float*)d_in[11];
  const float* Wh  = (const float*)d_in[12];
  const float* bl  = (const float*)d_in[13];
  const float* Wo  = (const float*)d_in[14];
  const float* bo  = (const float*)d_in[15];
  float* out = (float*)d_out;
  float* ws  = (float*)d_ws;

  float* keys = ws;                        // 1,048,576 f
  float* hs   = keys + 1048576;            //   524,288 f
  float* xch  = hs   + 524288;             //   147,456 f  (2*32*8*288)
  float* part = xch  + 147456;             //   512,000 f  (250*2048)
  unsigned* flags = (unsigned*)(part + 512000);  // 256 u32

  hipLaunchKernelGGL(k_keys, dim3(256), dim3(256), 0, stream, enc, Wk, bk, keys, flags);
  hipLaunchKernelGGL(k_mega, dim3(506), dim3(1024), 0, stream,
                     tok, h0, c0, enc, E, Wq, bq, Vw, bv, Wx, Wh, bl, Wo, bo,
                     keys, hs, xch, flags, out, part);
  hipLaunchKernelGGL(k_scale, dim3(2048), dim3(256), 0, stream, out, part);
}

// Round 7
// 2801.422 us; speedup vs baseline: 1.0891x; 1.0891x over previous
//
#include <hip/hip_runtime.h>

#define Bz 32
#define Tz 64
#define Sz 128
#define Dz 256
#define Vz 32000
#define NREC 128   // recurrence blocks (2 rows each)
#define NWRK 125   // logits worker blocks (256-col slice each)

__device__ __forceinline__ float sigmf(float x){ return 1.0f/(1.0f + __expf(-x)); }
__device__ __forceinline__ float tanhfast(float x){ float e = __expf(2.0f*x); return 1.0f - 2.0f/(e+1.0f); }

__device__ __forceinline__ void st_l3(float* p, float v){
  __hip_atomic_store(p, v, __ATOMIC_RELAXED, __HIP_MEMORY_SCOPE_AGENT);
}
__device__ __forceinline__ float ld_l3(const float* p){
  return __hip_atomic_load(p, __ATOMIC_RELAXED, __HIP_MEMORY_SCOPE_AGENT);
}

// ---------------- K_PREP: keys = enc@Wk + bk ; encW = enc@Wx[0:256,:] ; flag reset ----------
__global__ void __launch_bounds__(256) k_prep(const float* __restrict__ enc,
                                              const float* __restrict__ Wk,
                                              const float* __restrict__ bk,
                                              const float* __restrict__ Wx,
                                              float* __restrict__ keys,
                                              float* __restrict__ encW,
                                              unsigned* __restrict__ flags){
  const int blk = blockIdx.x, tid = threadIdx.x;
  if (blk == 0 && tid < 160) flags[tid] = 0u;      // 128 flags + 8 ctr (+pad)
  if (blk < 256){
    const int b  = blk >> 3;
    const int s0 = (blk & 7) * 16;
    const float* ebase = enc + (b*Sz + s0)*Dz;
    const int d = tid;
    float acc[16];
    #pragma unroll
    for (int i = 0; i < 16; ++i) acc[i] = 0.f;
    for (int k = 0; k < Dz; k += 4){
      float w0 = Wk[(k+0)*Dz + d], w1 = Wk[(k+1)*Dz + d];
      float w2 = Wk[(k+2)*Dz + d], w3 = Wk[(k+3)*Dz + d];
      #pragma unroll
      for (int si = 0; si < 16; ++si){
        float4 ev = *(const float4*)(ebase + si*Dz + k);
        acc[si] += ev.x*w0 + ev.y*w1 + ev.z*w2 + ev.w*w3;
      }
    }
    const float bkd = bk[d];
    #pragma unroll
    for (int si = 0; si < 16; ++si)
      keys[(b*Sz + s0 + si)*Dz + d] = acc[si] + bkd;
  } else {
    const int row0 = (blk - 256) * 4;              // 1024 blocks x 4 rows
    const int u4 = tid * 4;
    float4 a0 = {0,0,0,0}, a1 = {0,0,0,0}, a2 = {0,0,0,0}, a3 = {0,0,0,0};
    for (int d = 0; d < Dz; ++d){
      float4 wv = *(const float4*)(Wx + (size_t)d*1024 + u4);
      float e0 = enc[(size_t)(row0+0)*Dz + d];
      float e1 = enc[(size_t)(row0+1)*Dz + d];
      float e2 = enc[(size_t)(row0+2)*Dz + d];
      float e3 = enc[(size_t)(row0+3)*Dz + d];
      a0.x += e0*wv.x; a0.y += e0*wv.y; a0.z += e0*wv.z; a0.w += e0*wv.w;
      a1.x += e1*wv.x; a1.y += e1*wv.y; a1.z += e1*wv.z; a1.w += e1*wv.w;
      a2.x += e2*wv.x; a2.y += e2*wv.y; a2.z += e2*wv.z; a2.w += e2*wv.w;
      a3.x += e3*wv.x; a3.y += e3*wv.y; a3.z += e3*wv.z; a3.w += e3*wv.w;
    }
    *(float4*)(encW + (size_t)(row0+0)*1024 + u4) = a0;
    *(float4*)(encW + (size_t)(row0+1)*1024 + u4) = a1;
    *(float4*)(encW + (size_t)(row0+2)*1024 + u4) = a2;
    *(float4*)(encW + (size_t)(row0+3)*1024 + u4) = a3;
  }
}

// ---------------- MEGA: blocks 0..127 recurrence (2 rows each), 128..252 logits workers -----
__global__ void __launch_bounds__(1024, 4) k_mega(
    const int* __restrict__ tok, const float* __restrict__ h0, const float* __restrict__ c0,
    const float* __restrict__ Emb,
    const float* __restrict__ Wq, const float* __restrict__ bq,
    const float* __restrict__ Vw, const float* __restrict__ bv,
    const float* __restrict__ Wx, const float* __restrict__ Wh,
    const float* __restrict__ bl, const float* __restrict__ Wo,
    const float* __restrict__ bo, const float* __restrict__ keys,
    const float* __restrict__ encW,
    float* __restrict__ hs, float* xch, unsigned* flags, unsigned* ctr,
    float* __restrict__ out, float* __restrict__ part)
{
  __shared__ float smem[19456];    // 76 KB, carved per role
  const int tid = threadIdx.x;

  if (blockIdx.x < NREC){
    // ================= RECURRENCE: rows 2p, 2p+1 ; unit-slice s =================
    const int rid = blockIdx.x;
    const int s = rid & 7, p = rid >> 3;

    float* xe    = smem;             // [2][512]  emb(256)||h(256)
    float* qv    = xe + 1024;        // [2][256]
    float* vl    = qv + 512;         // [256]
    float* selds = vl + 256;         // [2][132]
    float* zp    = selds + 264;      // [2][1024]
    float* qpp   = zp + 2048;        // [2][2][256]
    float* hnl   = qpp + 1024;       // [2][32]
    float* clds  = hnl + 64;         // [2][32]

    const int u_local = tid & 127;
    const int kc = tid >> 7;
    const int u_gate = ((u_local >> 5) << 8) + (s << 5) + (u_local & 31);

    // persistent register weights
    float w[64];
    {
      const float* wbase = (kc < 4) ? (Wx + (size_t)(256 + kc*64)*1024 + u_gate)
                                    : (Wh + (size_t)((kc-4)*64)*1024 + u_gate);
      #pragma unroll
      for (int i = 0; i < 64; ++i) w[i] = wbase[(size_t)i*1024];
    }
    const int dq = tid & 255, rq = (tid >> 8) & 1, uh = tid >> 9;
    float wq[16];
    #pragma unroll
    for (int uu = 0; uu < 16; ++uu) wq[uu] = Wq[(size_t)(s*32 + uh*16 + uu)*Dz + dq];

    if (tid < Dz) vl[tid] = Vw[tid];
    if (tid < 64){
      int r = tid >> 5, u = tid & 31;
      hnl[r*32+u] = h0[(2*p+r)*Dz + s*32 + u];
      clds[r*32+u] = c0[(2*p+r)*Dz + s*32 + u];
    }
    __syncthreads();

    // initial publish (parity 0, token 1) + emb prefetch t=0
    {
      float qp = 0.f;
      #pragma unroll
      for (int uu = 0; uu < 16; ++uu) qp = __builtin_fmaf(hnl[rq*32 + uh*16 + uu], wq[uu], qp);
      qpp[(rq*2 + uh)*256 + dq] = qp;
    }
    __syncthreads();
    {
      float* xn = xch + (size_t)rid*576;
      if (tid < 512){
        int r = tid >> 8, d = tid & 255;
        st_l3(xn + r*288 + d, qpp[(r*2+0)*256 + d] + qpp[(r*2+1)*256 + d]);
        int tk = tok[(2*p + r)*Tz + 0];
        xe[r*512 + d] = Emb[(size_t)tk*Dz + d];
      } else if (tid < 576){
        int r = (tid - 512) >> 5, u = (tid - 512) & 31;
        st_l3(xn + r*288 + 256 + u, hnl[r*32 + u]);
      }
      __syncthreads();   // stores ack'd at L3
      if (tid == 0)
        __hip_atomic_store(flags + rid, 1u, __ATOMIC_RELAXED, __HIP_MEMORY_SCOPE_AGENT);
    }

    const float bv0 = bv[0];
    const int row2 = tid >> 9, ss = (tid >> 2) & 127, p4 = tid & 3;

    for (int t = 0; t < Tz; ++t){
      // P0: poll row-pair peers
      if (tid < 8){
        const unsigned tgt = (unsigned)(t + 1);
        while (__hip_atomic_load(flags + p*8 + tid, __ATOMIC_RELAXED, __HIP_MEMORY_SCOPE_AGENT) < tgt)
          __builtin_amdgcn_s_sleep(1);
      }
      __syncthreads();
      __builtin_amdgcn_fence(__ATOMIC_ACQUIRE, "workgroup");

      const float* xcp = xch + (size_t)((t & 1)*NREC + p*8)*576;
      // P1: assemble q (512 thr) and h (512 thr)
      if (tid < 512){
        int r = tid >> 8, d = tid & 255;
        float q = bq[d];
        #pragma unroll
        for (int s2 = 0; s2 < 8; ++s2) q += ld_l3(xcp + s2*576 + r*288 + d);
        qv[r*256 + d] = q;
      } else {
        int idx = tid - 512, r = idx >> 8, hu = idx & 255;
        xe[r*512 + 256 + hu] = ld_l3(xcp + (hu >> 5)*576 + r*288 + 256 + (hu & 31));
      }
      __syncthreads();
      // P2: scores + inline exp  (thread = row x ss x d-quarter)
      {
        const int bb_ = 2*p + row2;
        const float* kp = keys + (size_t)(bb_*Sz + ss)*Dz;
        const float* qp_ = qv + row2*256;
        float a = 0.f;
        #pragma unroll
        for (int j = 0; j < 16; ++j){
          const int d0 = j*16 + p4*4;
          float4 kv = *(const float4*)(kp + d0);
          float4 qj = *(const float4*)(qp_ + d0);
          float4 vj = *(const float4*)(vl + d0);
          a += tanhfast(qj.x + kv.x) * vj.x;
          a += tanhfast(qj.y + kv.y) * vj.y;
          a += tanhfast(qj.z + kv.z) * vj.z;
          a += tanhfast(qj.w + kv.w) * vj.w;
        }
        a += __shfl_down(a, 2);
        a += __shfl_down(a, 1);
        if (p4 == 0) selds[row2*132 + ss] = __expf(a + bv0);
      }
      __syncthreads();
      // P3: softmax denom (wave0 = row0, wave1 = row1)
      if (tid < 128){
        int r = tid >> 6, i = tid & 63;
        float v = selds[r*132 + i] + selds[r*132 + i + 64];
        #pragma unroll
        for (int off = 32; off > 0; off >>= 1) v += __shfl_down(v, off);
        if (i == 0) selds[r*132 + Sz] = 1.0f / v;
      }
      __syncthreads();
      // P4: z partials for both rows (register gate weights + global encW)
      {
        float a1a = 0.f, a1b = 0.f;
        const float* xea = xe + kc*64;
        const float* xeb = xe + 512 + kc*64;
        #pragma unroll
        for (int i4 = 0; i4 < 16; ++i4){
          float4 xva = *(const float4*)(xea + i4*4);
          float4 xvb = *(const float4*)(xeb + i4*4);
          a1a += xva.x*w[i4*4+0] + xva.y*w[i4*4+1] + xva.z*w[i4*4+2] + xva.w*w[i4*4+3];
          a1b += xvb.x*w[i4*4+0] + xvb.y*w[i4*4+1] + xvb.z*w[i4*4+2] + xvb.w*w[i4*4+3];
        }
        float a2a = 0.f, a2b = 0.f;
        const float* ewa = encW + (size_t)((2*p)*Sz + kc*16)*1024 + u_gate;
        const float* ewb = ewa + (size_t)Sz*1024;
        #pragma unroll
        for (int m = 0; m < 16; ++m){
          a2a = __builtin_fmaf(selds[kc*16 + m],       ewa[(size_t)m*1024], a2a);
          a2b = __builtin_fmaf(selds[132 + kc*16 + m], ewb[(size_t)m*1024], a2b);
        }
        zp[kc*128 + u_local]        = a1a + selds[Sz]*a2a;
        zp[1024 + kc*128 + u_local] = a1b + selds[132 + Sz]*a2b;
      }
      __syncthreads();
      // P5: gate reduce + LSTM + hs publish
      if (tid < 64){
        int r = tid >> 5, u = tid & 31;
        float zi = bl[       s*32 + u], zf = bl[  Dz + s*32 + u];
        float zg = bl[2*Dz + s*32 + u], zo = bl[3*Dz + s*32 + u];
        const float* zpr = zp + r*1024;
        #pragma unroll
        for (int k2 = 0; k2 < 8; ++k2){
          zi += zpr[k2*128 +      u];
          zf += zpr[k2*128 + 32 + u];
          zg += zpr[k2*128 + 64 + u];
          zo += zpr[k2*128 + 96 + u];
        }
        float cn = sigmf(zf)*clds[r*32+u] + sigmf(zi)*tanhfast(zg);
        float hn = sigmf(zo)*tanhfast(cn);
        clds[r*32+u] = cn; hnl[r*32+u] = hn;
        st_l3(hs + (size_t)(t*Bz + 2*p + r)*Dz + s*32 + u, hn);
      }
      __syncthreads();
      // P6a: q-partials for t+1
      {
        float qp = 0.f;
        #pragma unroll
        for (int uu = 0; uu < 16; ++uu) qp = __builtin_fmaf(hnl[rq*32 + uh*16 + uu], wq[uu], qp);
        qpp[(rq*2 + uh)*256 + dq] = qp;
      }
      __syncthreads();
      // P6b: publish exchange + emb prefetch t+1
      {
        float* xn = xch + (size_t)(((t+1) & 1)*NREC + rid)*576;
        if (tid < 512){
          int r = tid >> 8, d = tid & 255;
          st_l3(xn + r*288 + d, qpp[(r*2+0)*256 + d] + qpp[(r*2+1)*256 + d]);
          if (t + 1 < Tz){
            int tk = tok[(2*p + r)*Tz + t + 1];
            xe[r*512 + d] = Emb[(size_t)tk*Dz + d];
          }
        } else if (tid < 576){
          int r = (tid - 512) >> 5, u = (tid - 512) & 31;
          st_l3(xn + r*288 + 256 + u, hnl[r*32 + u]);
        }
        __syncthreads();   // all stores (incl hs) ack'd at L3
        if (tid == 0)
          __hip_atomic_store(flags + rid, (unsigned)(t + 2), __ATOMIC_RELAXED, __HIP_MEMORY_SCOPE_AGENT);
      }
    }
  } else {
    // ================= LOGITS WORKER: fixed 256-col slice, 8 row-chunks of 256 =================
    const int wid = blockIdx.x - NREC;     // 0..124
    const int c0 = wid * 256;
    float* As     = smem;                  // [32][260]
    float* Bs     = As + 32*260;           // [32][260]
    float* rs_row = Bs + 32*260;           // [256]
    float* rq4    = rs_row + 256;          // [256][4]
    float* rinv   = rq4 + 1024;            // [256]

    const int ty = tid >> 5, tx = tid & 31;
    float bo8[8];
    #pragma unroll
    for (int jj = 0; jj < 8; ++jj) bo8[jj] = bo[c0 + tx + 32*jj];

    for (int y = 0; y < 8; ++y){
      // wait: all 128 recur blocks past step 8y+7  (hs rows of chunk y final)
      const unsigned tgt = (unsigned)(8*y + 9);
      for (;;){
        int ok = 1;
        if (tid < NREC)
          ok = (__hip_atomic_load(flags + tid, __ATOMIC_RELAXED, __HIP_MEMORY_SCOPE_AGENT) >= tgt);
        if (__syncthreads_count(ok) == 1024) break;
        __builtin_amdgcn_s_sleep(16);
      }
      __builtin_amdgcn_fence(__ATOMIC_ACQUIRE, "workgroup");

      const int R0 = y * 256;
      float acc[8][8];
      #pragma unroll
      for (int i = 0; i < 8; ++i)
        #pragma unroll
        for (int j = 0; j < 8; ++j) acc[i][j] = 0.f;

      for (int k0 = 0; k0 < Dz; k0 += 32){
        #pragma unroll
        for (int i = 0; i < 2; ++i){     // stage A^T [k][r]
          int idx = tid + i*1024;
          int r = idx >> 3, kq = idx & 7;
          float4 hv = *(const float4*)(hs + (size_t)(R0 + r)*Dz + k0 + kq*4);
          As[(kq*4+0)*260 + r] = hv.x; As[(kq*4+1)*260 + r] = hv.y;
          As[(kq*4+2)*260 + r] = hv.z; As[(kq*4+3)*260 + r] = hv.w;
        }
        #pragma unroll
        for (int i = 0; i < 2; ++i){     // stage B [k][c]
          int idx = tid + i*1024;
          int kk = idx >> 6, cq = idx & 63;
          float4 wv = *(const float4*)(Wo + (size_t)(k0 + kk)*Vz + c0 + cq*4);
          *(float4*)(Bs + kk*260 + cq*4) = wv;
        }
        __syncthreads();
        #pragma unroll
        for (int kk = 0; kk < 32; ++kk){
          float4 av0 = *(const float4*)(As + kk*260 + ty*8);
          float4 av1 = *(const float4*)(As + kk*260 + ty*8 + 4);
          float ar[8] = {av0.x,av0.y,av0.z,av0.w,av1.x,av1.y,av1.z,av1.w};
          float br[8];
          #pragma unroll
          for (int jj = 0; jj < 8; ++jj) br[jj] = Bs[kk*260 + tx + 32*jj];   // conflict-free
          #pragma unroll
          for (int i = 0; i < 8; ++i)
            #pragma unroll
            for (int j = 0; j < 8; ++j)
              acc[i][j] = __builtin_fmaf(ar[i], br[j], acc[i][j]);
        }
        __syncthreads();
      }
      // exp + per-row partial sums (shfl over tx half-wave)
      #pragma unroll
      for (int i = 0; i < 8; ++i){
        float rp_ = 0.f;
        #pragma unroll
        for (int j = 0; j < 8; ++j){
          acc[i][j] = __expf(acc[i][j] + bo8[j]);
          rp_ += acc[i][j];
        }
        #pragma unroll
        for (int off = 16; off > 0; off >>= 1) rp_ += __shfl_down(rp_, off);
        if (tx == 0) rs_row[ty*8 + i] = rp_;
      }
      __syncthreads();
      if (tid < 256)
        st_l3(part + (size_t)wid*2048 + R0 + tid, rs_row[tid]);
      __syncthreads();   // part stores ack'd at L3
      if (tid == 0){
        __hip_atomic_fetch_add(ctr + y, 1u, __ATOMIC_RELAXED, __HIP_MEMORY_SCOPE_AGENT);
        while (__hip_atomic_load(ctr + y, __ATOMIC_RELAXED, __HIP_MEMORY_SCOPE_AGENT) < (unsigned)NWRK)
          __builtin_amdgcn_s_sleep(8);
      }
      __syncthreads();
      __builtin_amdgcn_fence(__ATOMIC_ACQUIRE, "workgroup");
      // deterministic rowsum: fixed-order partials over 125 col-slices
      {
        int r4 = tid >> 2, q4 = tid & 3;
        int nct = (q4 < 3) ? 32 : 29;
        float sacc = 0.f;
        for (int c2 = 0; c2 < nct; ++c2)
          sacc += ld_l3(part + (size_t)(q4*32 + c2)*2048 + R0 + r4);
        rq4[r4*4 + q4] = sacc;
      }
      __syncthreads();
      if (tid < 256)
        rinv[tid] = 1.0f / (rq4[tid*4] + rq4[tid*4+1] + rq4[tid*4+2] + rq4[tid*4+3]);
      __syncthreads();
      // scale + final write
      #pragma unroll
      for (int i = 0; i < 8; ++i){
        const int R = R0 + ty*8 + i;
        const int orow = (R & 31)*64 + (R >> 5);   // R = t*32+b -> out row b*64+t
        const float iv = rinv[ty*8 + i];
        float* orp = out + (size_t)orow*Vz + c0;
        #pragma unroll
        for (int jj = 0; jj < 8; ++jj)
          orp[tx + 32*jj] = acc[i][jj] * iv;
      }
      __syncthreads();   // protect LDS reuse next chunk
    }
  }
}

extern "C" void kernel_launch(void* const* d_in, const int* in_sizes, int n_in,
                              void* d_out, int out_size, void* d_ws, size_t ws_size,
                              hipStream_t stream){
  const int*   tok = (const int*)  d_in[0];
  const float* h0  = (const float*)d_in[1];
  const float* c0  = (const float*)d_in[2];
  const float* enc = (const float*)d_in[3];
  const float* E   = (const float*)d_in[4];
  const float* Wq  = (const float*)d_in[5];
  const float* bq  = (const float*)d_in[6];
  const float* Wk  = (const float*)d_in[7];
  const float* bk  = (const float*)d_in[8];
  const float* Vw  = (const float*)d_in[9];
  const float* bv  = (const float*)d_in[10];
  const float* Wx  = (const float*)d_in[11];
  const float* Wh  = (const float*)d_in[12];
  const float* bl  = (const float*)d_in[13];
  const float* Wo  = (const float*)d_in[14];
  const float* bo  = (const float*)d_in[15];
  float* out = (float*)d_out;
  float* ws  = (float*)d_ws;

  float* keys = ws;                        // 1,048,576 f
  float* encW = keys + 1048576;            // 4,194,304 f
  float* hs   = encW + 4194304;            //   524,288 f
  float* xch  = hs   + 524288;             //   147,456 f  (2 parity x 128 blk x 576)
  float* part = xch  + 147456;             //   256,000 f  (125 x 2048)
  unsigned* flags = (unsigned*)(part + 256000);  // 128 flags
  unsigned* ctr   = flags + 128;                 // 8 chunk counters

  hipLaunchKernelGGL(k_prep, dim3(1280), dim3(256), 0, stream,
                     enc, Wk, bk, Wx, keys, encW, flags);
  hipLaunchKernelGGL(k_mega, dim3(NREC + NWRK), dim3(1024), 0, stream,
                     tok, h0, c0, E, Wq, bq, Vw, bv, Wx, Wh, bl, Wo, bo,
                     keys, encW, hs, xch, flags, ctr, out, part);
}

// Round 8
// 2473.919 us; speedup vs baseline: 1.2332x; 1.1324x over previous
//
#include <hip/hip_runtime.h>

#define Bz 32
#define Tz 64
#define Sz 128
#define Dz 256
#define Vz 32000
#define NWRK 125   // active logits workers (256-col slice each)

__device__ __forceinline__ float sigmf(float x){ return 1.0f/(1.0f + __expf(-x)); }
__device__ __forceinline__ float tanhfast(float x){ float e = __expf(2.0f*x); return 1.0f - 2.0f/(e+1.0f); }

__device__ __forceinline__ void st_l3(float* p, float v){
  __hip_atomic_store(p, v, __ATOMIC_RELAXED, __HIP_MEMORY_SCOPE_AGENT);
}
__device__ __forceinline__ float ld_l3(const float* p){
  return __hip_atomic_load(p, __ATOMIC_RELAXED, __HIP_MEMORY_SCOPE_AGENT);
}

// ---------------- K_PREP: keys = enc@Wk + bk ; encW = enc@Wx[0:256,:] ; flag reset ----------
__global__ void __launch_bounds__(256) k_prep(const float* __restrict__ enc,
                                              const float* __restrict__ Wk,
                                              const float* __restrict__ bk,
                                              const float* __restrict__ Wx,
                                              float* __restrict__ keys,
                                              float* __restrict__ encW,
                                              unsigned* __restrict__ flags){
  const int blk = blockIdx.x, tid = threadIdx.x;
  if (blk == 0 && tid < 160) flags[tid] = 0u;      // 128 flags + 16 ctr (+pad)
  if (blk < 256){
    const int b  = blk >> 3;
    const int s0 = (blk & 7) * 16;
    const float* ebase = enc + (b*Sz + s0)*Dz;
    const int d = tid;
    float acc[16];
    #pragma unroll
    for (int i = 0; i < 16; ++i) acc[i] = 0.f;
    for (int k = 0; k < Dz; k += 4){
      float w0 = Wk[(k+0)*Dz + d], w1 = Wk[(k+1)*Dz + d];
      float w2 = Wk[(k+2)*Dz + d], w3 = Wk[(k+3)*Dz + d];
      #pragma unroll
      for (int si = 0; si < 16; ++si){
        float4 ev = *(const float4*)(ebase + si*Dz + k);
        acc[si] += ev.x*w0 + ev.y*w1 + ev.z*w2 + ev.w*w3;
      }
    }
    const float bkd = bk[d];
    #pragma unroll
    for (int si = 0; si < 16; ++si)
      keys[(b*Sz + s0 + si)*Dz + d] = acc[si] + bkd;
  } else {
    const int row0 = (blk - 256) * 4;              // 1024 blocks x 4 rows
    const int u4 = tid * 4;
    float4 a0 = {0,0,0,0}, a1 = {0,0,0,0}, a2 = {0,0,0,0}, a3 = {0,0,0,0};
    for (int d = 0; d < Dz; ++d){
      float4 wv = *(const float4*)(Wx + (size_t)d*1024 + u4);
      float e0 = enc[(size_t)(row0+0)*Dz + d];
      float e1 = enc[(size_t)(row0+1)*Dz + d];
      float e2 = enc[(size_t)(row0+2)*Dz + d];
      float e3 = enc[(size_t)(row0+3)*Dz + d];
      a0.x += e0*wv.x; a0.y += e0*wv.y; a0.z += e0*wv.z; a0.w += e0*wv.w;
      a1.x += e1*wv.x; a1.y += e1*wv.y; a1.z += e1*wv.z; a1.w += e1*wv.w;
      a2.x += e2*wv.x; a2.y += e2*wv.y; a2.z += e2*wv.z; a2.w += e2*wv.w;
      a3.x += e3*wv.x; a3.y += e3*wv.y; a3.z += e3*wv.z; a3.w += e3*wv.w;
    }
    *(float4*)(encW + (size_t)(row0+0)*1024 + u4) = a0;
    *(float4*)(encW + (size_t)(row0+1)*1024 + u4) = a1;
    *(float4*)(encW + (size_t)(row0+2)*1024 + u4) = a2;
    *(float4*)(encW + (size_t)(row0+3)*1024 + u4) = a3;
  }
}

// ---------------- MEGA: XCD-partitioned. blk%8<4 -> recurrence, blk%8>=4 -> logits worker ----
// Recur block: rows 2p,2p+1, unit-slice s; p = xcd*4 + (w>>3), s = w&7 (all 8 peers of a
// row-pair on ONE XCD -> keys/Wx/Wh slices L2-resident, no worker thrash). encW slice in LDS.
// waves_per_eu(4,4): exactly 16 waves/CU -> full 128-VGPR budget, 1 block/CU.
__global__ void __attribute__((amdgpu_flat_work_group_size(1024,1024), amdgpu_waves_per_eu(4,4)))
k_mega(
    const int* __restrict__ tok, const float* __restrict__ h0, const float* __restrict__ c0,
    const float* __restrict__ Emb,
    const float* __restrict__ Wq, const float* __restrict__ bq,
    const float* __restrict__ Vw, const float* __restrict__ bv,
    const float* __restrict__ Wx, const float* __restrict__ Wh,
    const float* __restrict__ bl, const float* __restrict__ Wo,
    const float* __restrict__ bo, const float* __restrict__ keys,
    const float* __restrict__ encW,
    float* __restrict__ hs, float* xch, unsigned* flags, unsigned* ctr,
    float* __restrict__ out, float* __restrict__ part)
{
  __shared__ float smem[38024];    // 152,096 B  (forces 1 block/CU too)
  const int tid = threadIdx.x;
  const int xcd = blockIdx.x & 7;
  const int widx = blockIdx.x >> 3;   // 0..31 within-XCD index

  if (xcd < 4){
    // ================= RECURRENCE: rows 2p,2p+1 ; unit-slice s =================
    const int p = xcd*4 + (widx >> 3);   // 0..15
    const int s = widx & 7;              // 0..7
    const int lidx = p*8 + s;            // logical flag/xch index

    float* ew    = smem;             // [2][128 srow][128 u_local] = 32768
    float* xe    = ew + 32768;       // [2][512]  emb||h
    float* qv    = xe + 1024;        // [2][256]
    float* vl    = qv + 512;         // [256]
    float* selds = vl + 256;         // [2][132]
    float* zp    = selds + 264;      // [2][1024]
    float* qpp   = zp + 2048;        // [4][256]
    float* hnl   = qpp + 1024;       // [2][32]
    float* clds  = hnl + 64;         // [2][32]

    const int u_local = tid & 127;
    const int kc = tid >> 7;
    const int u_gate = ((u_local >> 5) << 8) + (s << 5) + (u_local & 31);

    // --- stage encW slice (2 rows x 128 srow x 128 cols) into LDS ---
    #pragma unroll
    for (int i = 0; i < 32; ++i){
      int gidx = tid + i*1024;
      int r = gidx >> 14, rem = gidx & 16383;
      int srow = rem >> 7, ul = rem & 127;
      int ug = ((ul >> 5) << 8) + (s << 5) + (ul & 31);
      ew[gidx] = encW[(size_t)((2*p + r)*Sz + srow)*1024 + ug];
    }

    // --- persistent register weights ---
    float w[64];
    {
      const float* wbase = (kc < 4) ? (Wx + (size_t)(256 + kc*64)*1024 + u_gate)
                                    : (Wh + (size_t)((kc-4)*64)*1024 + u_gate);
      #pragma unroll
      for (int i = 0; i < 64; ++i) w[i] = wbase[(size_t)i*1024];
    }
    const int dq = tid & 255, rq = (tid >> 8) & 1, uh = tid >> 9;
    float wq[16];
    #pragma unroll
    for (int uu = 0; uu < 16; ++uu) wq[uu] = Wq[(size_t)(s*32 + uh*16 + uu)*Dz + dq];

    if (tid < Dz) vl[tid] = Vw[tid];
    if (tid < 64){
      int r = tid >> 5, u = tid & 31;
      hnl[r*32+u] = h0[(2*p+r)*Dz + s*32 + u];
      clds[r*32+u] = c0[(2*p+r)*Dz + s*32 + u];
    }
    __syncthreads();

    // --- initial publish (parity 0, token 1) + emb prefetch t=0 ---
    {
      float qp = 0.f;
      #pragma unroll
      for (int uu = 0; uu < 16; ++uu) qp = __builtin_fmaf(hnl[rq*32 + uh*16 + uu], wq[uu], qp);
      qpp[(rq*2 + uh)*256 + dq] = qp;
    }
    __syncthreads();
    {
      float* xn = xch + (size_t)lidx*576;
      if (tid < 512){
        int r = tid >> 8, d = tid & 255;
        st_l3(xn + r*288 + d, qpp[(r*2+0)*256 + d] + qpp[(r*2+1)*256 + d]);
        int tk = tok[(2*p + r)*Tz + 0];
        xe[r*512 + d] = Emb[(size_t)tk*Dz + d];
      } else if (tid < 576){
        int r = (tid - 512) >> 5, u = (tid - 512) & 31;
        st_l3(xn + r*288 + 256 + u, hnl[r*32 + u]);
      }
      __syncthreads();   // stores ack'd at L3
      if (tid == 0)
        __hip_atomic_store(flags + lidx, 1u, __ATOMIC_RELAXED, __HIP_MEMORY_SCOPE_AGENT);
    }

    const float bv0 = bv[0];
    const int row2 = tid >> 9, ss = (tid >> 2) & 127, p4 = tid & 3;

    for (int t = 0; t < Tz; ++t){
      // P0: poll the 8 peers of this row-pair
      if (tid < 8){
        const unsigned tgt = (unsigned)(t + 1);
        while (__hip_atomic_load(flags + p*8 + tid, __ATOMIC_RELAXED, __HIP_MEMORY_SCOPE_AGENT) < tgt)
          __builtin_amdgcn_s_sleep(1);
      }
      __syncthreads();
      __builtin_amdgcn_fence(__ATOMIC_ACQUIRE, "workgroup");

      const float* xcp = xch + (size_t)((t & 1)*128 + p*8)*576;
      // P1: assemble q (512 thr) and h (512 thr)
      if (tid < 512){
        int r = tid >> 8, d = tid & 255;
        float q = bq[d];
        #pragma unroll
        for (int s2 = 0; s2 < 8; ++s2) q += ld_l3(xcp + s2*576 + r*288 + d);
        qv[r*256 + d] = q;
      } else {
        int idx = tid - 512, r = idx >> 8, hu = idx & 255;
        xe[r*512 + 256 + hu] = ld_l3(xcp + (hu >> 5)*576 + r*288 + 256 + (hu & 31));
      }
      __syncthreads();
      // P2: scores + inline exp
      {
        const int bb_ = 2*p + row2;
        const float* kp = keys + (size_t)(bb_*Sz + ss)*Dz;
        const float* qp_ = qv + row2*256;
        float a = 0.f;
        #pragma unroll
        for (int j = 0; j < 16; ++j){
          const int d0 = j*16 + p4*4;
          float4 kv = *(const float4*)(kp + d0);
          float4 qj = *(const float4*)(qp_ + d0);
          float4 vj = *(const float4*)(vl + d0);
          a += tanhfast(qj.x + kv.x) * vj.x;
          a += tanhfast(qj.y + kv.y) * vj.y;
          a += tanhfast(qj.z + kv.z) * vj.z;
          a += tanhfast(qj.w + kv.w) * vj.w;
        }
        a += __shfl_down(a, 2);
        a += __shfl_down(a, 1);
        if (p4 == 0) selds[row2*132 + ss] = __expf(a + bv0);
      }
      __syncthreads();
      // P3: softmax denom
      if (tid < 128){
        int r = tid >> 6, i = tid & 63;
        float v = selds[r*132 + i] + selds[r*132 + i + 64];
        #pragma unroll
        for (int off = 32; off > 0; off >>= 1) v += __shfl_down(v, off);
        if (i == 0) selds[r*132 + Sz] = 1.0f / v;
      }
      __syncthreads();
      // P4: z partials (register gate weights + LDS encW)
      {
        float a1a = 0.f, a1b = 0.f;
        const float* xea = xe + kc*64;
        const float* xeb = xe + 512 + kc*64;
        #pragma unroll
        for (int i4 = 0; i4 < 16; ++i4){
          float4 xva = *(const float4*)(xea + i4*4);
          float4 xvb = *(const float4*)(xeb + i4*4);
          a1a += xva.x*w[i4*4+0] + xva.y*w[i4*4+1] + xva.z*w[i4*4+2] + xva.w*w[i4*4+3];
          a1b += xvb.x*w[i4*4+0] + xvb.y*w[i4*4+1] + xvb.z*w[i4*4+2] + xvb.w*w[i4*4+3];
        }
        float a2a = 0.f, a2b = 0.f;
        const float* ewa = ew + (kc*16)*128 + u_local;
        const float* ewb = ewa + 16384;
        #pragma unroll
        for (int m = 0; m < 16; ++m){
          a2a = __builtin_fmaf(selds[kc*16 + m],       ewa[m*128], a2a);
          a2b = __builtin_fmaf(selds[132 + kc*16 + m], ewb[m*128], a2b);
        }
        zp[kc*128 + u_local]        = a1a + selds[Sz]*a2a;
        zp[1024 + kc*128 + u_local] = a1b + selds[132 + Sz]*a2b;
      }
      __syncthreads();
      // P5: gate reduce + LSTM + hs publish
      if (tid < 64){
        int r = tid >> 5, u = tid & 31;
        float zi = bl[       s*32 + u], zf = bl[  Dz + s*32 + u];
        float zg = bl[2*Dz + s*32 + u], zo = bl[3*Dz + s*32 + u];
        const float* zpr = zp + r*1024;
        #pragma unroll
        for (int k2 = 0; k2 < 8; ++k2){
          zi += zpr[k2*128 +      u];
          zf += zpr[k2*128 + 32 + u];
          zg += zpr[k2*128 + 64 + u];
          zo += zpr[k2*128 + 96 + u];
        }
        float cn = sigmf(zf)*clds[r*32+u] + sigmf(zi)*tanhfast(zg);
        float hn = sigmf(zo)*tanhfast(cn);
        clds[r*32+u] = cn; hnl[r*32+u] = hn;
        st_l3(hs + (size_t)(t*Bz + 2*p + r)*Dz + s*32 + u, hn);
      }
      __syncthreads();
      // P6a: q-partials for t+1
      {
        float qp = 0.f;
        #pragma unroll
        for (int uu = 0; uu < 16; ++uu) qp = __builtin_fmaf(hnl[rq*32 + uh*16 + uu], wq[uu], qp);
        qpp[(rq*2 + uh)*256 + dq] = qp;
      }
      __syncthreads();
      // P6b: publish exchange + emb prefetch t+1
      {
        float* xn = xch + (size_t)(((t+1) & 1)*128 + lidx)*576;
        if (tid < 512){
          int r = tid >> 8, d = tid & 255;
          st_l3(xn + r*288 + d, qpp[(r*2+0)*256 + d] + qpp[(r*2+1)*256 + d]);
          if (t + 1 < Tz){
            int tk = tok[(2*p + r)*Tz + t + 1];
            xe[r*512 + d] = Emb[(size_t)tk*Dz + d];
          }
        } else if (tid < 576){
          int r = (tid - 512) >> 5, u = (tid - 512) & 31;
          st_l3(xn + r*288 + 256 + u, hnl[r*32 + u]);
        }
        __syncthreads();   // all stores (incl hs) ack'd at L3
        if (tid == 0)
          __hip_atomic_store(flags + lidx, (unsigned)(t + 2), __ATOMIC_RELAXED, __HIP_MEMORY_SCOPE_AGENT);
      }
    }
  } else {
    // ================= LOGITS WORKER: 256-col slice, 16 row-chunks of 128 =================
    const int wid = (xcd - 4)*32 + widx;   // 0..127
    if (wid >= NWRK) return;               // 3 idle
    const int c0 = wid * 256;
    float* As     = smem;                  // [128][36]
    float* Bs     = As + 128*36;           // [32][264]
    float* rs_row = Bs + 32*264;           // [128]
    float* rq4    = rs_row + 128;          // [128][4]
    float* rinv   = rq4 + 512;             // [128]

    const int ty = tid >> 5, tx = tid & 31;   // ty 0..31 (4 rows each), tx 0..31
    float bo8[8];
    #pragma unroll
    for (int jj = 0; jj < 8; ++jj) bo8[jj] = bo[c0 + tx + 32*jj];

    for (int y = 0; y < 16; ++y){
      // wait: all 128 recur blocks past step 4y+3
      const unsigned tgt = (unsigned)(4*y + 5);
      for (;;){
        int ok = 1;
        if (tid < 128)
          ok = (__hip_atomic_load(flags + tid, __ATOMIC_RELAXED, __HIP_MEMORY_SCOPE_AGENT) >= tgt);
        if (__syncthreads_count(ok) == 1024) break;
        __builtin_amdgcn_s_sleep(16);
      }
      __builtin_amdgcn_fence(__ATOMIC_ACQUIRE, "workgroup");

      const int R0 = y * 128;
      float acc[4][8];
      #pragma unroll
      for (int i = 0; i < 4; ++i)
        #pragma unroll
        for (int j = 0; j < 8; ++j) acc[i][j] = 0.f;

      for (int k0 = 0; k0 < Dz; k0 += 32){
        { // stage A [r][k] row-major (1 float4/thread); first touch is post-flag -> L3-coherent
          int r = tid >> 3, kq = tid & 7;
          float4 hv = *(const float4*)(hs + (size_t)(R0 + r)*Dz + k0 + kq*4);
          *(float4*)(As + r*36 + kq*4) = hv;
        }
        #pragma unroll
        for (int i = 0; i < 2; ++i){   // stage B [k][c]
          int idx = tid + i*1024;
          int kk = idx >> 6, cq = idx & 63;
          float4 wv = *(const float4*)(Wo + (size_t)(k0 + kk)*Vz + c0 + cq*4);
          *(float4*)(Bs + kk*264 + cq*4) = wv;
        }
        __syncthreads();
        #pragma unroll
        for (int kk = 0; kk < 32; ++kk){
          float ar[4], br[8];
          #pragma unroll
          for (int i = 0; i < 4; ++i) ar[i] = As[(ty*4+i)*36 + kk];
          #pragma unroll
          for (int jj = 0; jj < 8; ++jj) br[jj] = Bs[kk*264 + tx + 32*jj];
          #pragma unroll
          for (int i = 0; i < 4; ++i)
            #pragma unroll
            for (int j = 0; j < 8; ++j)
              acc[i][j] = __builtin_fmaf(ar[i], br[j], acc[i][j]);
        }
        __syncthreads();
      }
      // exp + per-row sums
      #pragma unroll
      for (int i = 0; i < 4; ++i){
        float rp_ = 0.f;
        #pragma unroll
        for (int j = 0; j < 8; ++j){
          acc[i][j] = __expf(acc[i][j] + bo8[j]);
          rp_ += acc[i][j];
        }
        #pragma unroll
        for (int off = 16; off > 0; off >>= 1) rp_ += __shfl_down(rp_, off);
        if (tx == 0) rs_row[ty*4 + i] = rp_;
      }
      __syncthreads();
      if (tid < 128)
        st_l3(part + (size_t)wid*2048 + R0 + tid, rs_row[tid]);
      __syncthreads();   // part stores ack'd at L3
      if (tid == 0){
        __hip_atomic_fetch_add(ctr + y, 1u, __ATOMIC_RELAXED, __HIP_MEMORY_SCOPE_AGENT);
        while (__hip_atomic_load(ctr + y, __ATOMIC_RELAXED, __HIP_MEMORY_SCOPE_AGENT) < (unsigned)NWRK)
          __builtin_amdgcn_s_sleep(8);
      }
      __syncthreads();
      __builtin_amdgcn_fence(__ATOMIC_ACQUIRE, "workgroup");
      // deterministic rowsum over 125 slices (fixed order)
      if (tid < 512){
        int r4 = tid >> 2, q4 = tid & 3;
        int nct = (q4 < 3) ? 32 : 29;
        float sacc = 0.f;
        for (int c2 = 0; c2 < nct; ++c2)
          sacc += ld_l3(part + (size_t)(q4*32 + c2)*2048 + R0 + r4);
        rq4[r4*4 + q4] = sacc;
      }
      __syncthreads();
      if (tid < 128)
        rinv[tid] = 1.0f / (rq4[tid*4] + rq4[tid*4+1] + rq4[tid*4+2] + rq4[tid*4+3]);
      __syncthreads();
      // scale + final write
      #pragma unroll
      for (int i = 0; i < 4; ++i){
        const int R = R0 + ty*4 + i;
        const int orow = (R & 31)*64 + (R >> 5);   // R = t*32+b -> out row b*64+t
        const float iv = rinv[ty*4 + i];
        float* orp = out + (size_t)orow*Vz + c0;
        #pragma unroll
        for (int jj = 0; jj < 8; ++jj)
          orp[tx + 32*jj] = acc[i][jj] * iv;
      }
      __syncthreads();   // protect LDS reuse next chunk
    }
  }
}

extern "C" void kernel_launch(void* const* d_in, const int* in_sizes, int n_in,
                              void* d_out, int out_size, void* d_ws, size_t ws_size,
                              hipStream_t stream){
  const int*   tok = (const int*)  d_in[0];
  const float* h0  = (const float*)d_in[1];
  const float* c0  = (const float*)d_in[2];
  const float* enc = (const float*)d_in[3];
  const float* E   = (const float*)d_in[4];
  const float* Wq  = (const float*)d_in[5];
  const float* bq  = (const float*)d_in[6];
  const float* Wk  = (const float*)d_in[7];
  const float* bk  = (const float*)d_in[8];
  const float* Vw  = (const float*)d_in[9];
  const float* bv  = (const float*)d_in[10];
  const float* Wx  = (const float*)d_in[11];
  const float* Wh  = (const float*)d_in[12];
  const float* bl  = (const float*)d_in[13];
  const float* Wo  = (const float*)d_in[14];
  const float* bo  = (const float*)d_in[15];
  float* out = (float*)d_out;
  float* ws  = (float*)d_ws;

  float* keys = ws;                        // 1,048,576 f
  float* encW = keys + 1048576;            // 4,194,304 f
  float* hs   = encW + 4194304;            //   524,288 f
  float* xch  = hs   + 524288;             //   147,456 f  (2 parity x 128 x 576)
  float* part = xch  + 147456;             //   256,000 f  (125 x 2048)
  unsigned* flags = (unsigned*)(part + 256000);  // 128 flags
  unsigned* ctr   = flags + 128;                 // 16 chunk counters

  hipLaunchKernelGGL(k_prep, dim3(1280), dim3(256), 0, stream,
                     enc, Wk, bk, Wx, keys, encW, flags);
  hipLaunchKernelGGL(k_mega, dim3(256), dim3(1024), 0, stream,
                     tok, h0, c0, E, Wq, bq, Vw, bv, Wx, Wh, bl, Wo, bo,
                     keys, encW, hs, xch, flags, ctr, out, part);
}